// Round 5
// baseline (235.145 us; speedup 1.0000x reference)
//
#include <hip/hip_runtime.h>

// CrossCompressUnit: fp32 in / fp32 out (verified R3/R7: passed, absmax 1.6e-2).
// B=262144 rows, D=64. 16 lanes/row, float4 chunk per lane per tensor.
// R5: pure-VALU DPP row reduction (masks {15,7,2,1}) — NEUTRAL vs __shfl_xor
//     -> reduction is not on the critical path. Kept (cheaper, no LDS pipe).
// R7: persistent grid-stride, 8 chunks/thread, weights hoisted (8x amortize),
//     depth-1 prefetch — NEUTRAL (234.3 us). Issue structure ruled out.
// R8: nt+sc0+sc1 cache-bypass stores — INCORRECT: bypassing stores race the
//     harness's cache-resident dirty output lines (out_e half, most recently
//     filled, read back stale; out_v half, already evicted, passed).
//     Cache-bypass is unsafe here; writeback traffic is harness-imposed.
// R9: revert to R7 exactly (last passing state).
// Model: dur_us ~= 2 harness poison fills (~2x79us, fixed) + kernel ~75us
//     = (256 MiB compulsory + ~256 MiB dirty-poison writeback) @ ~6.8 TB/s.
//     Three structural variants (one-shot shuffle / one-shot DPP / persistent
//     prefetch) all land 233.5-236 us -> traffic-limited, at effective floor.

using f32x4 = __attribute__((ext_vector_type(4))) float;

constexpr int D_DIM = 64;
constexpr int B_ROWS = 262144;
constexpr int LANES_PER_ROW = 16;                       // 16 lanes x 4 elems = 64
constexpr int CHUNKS = B_ROWS * LANES_PER_ROW;          // 4,194,304 f32x4/tensor
constexpr int BLOCK = 256;
constexpr int NBLOCKS = 2048;                           // 8 blocks/CU nominal
constexpr int NTHREADS = BLOCK * NBLOCKS;               // 524,288
constexpr int PER_THREAD = CHUNKS / NTHREADS;           // 8
constexpr int STRIDE = NTHREADS;                        // % 16 == 0 -> sub fixed

__device__ __forceinline__ float dot4(const f32x4 a, const f32x4 b) {
    return a[0]*b[0] + a[1]*b[1] + a[2]*b[2] + a[3]*b[3];
}

// x += DPP-permuted(x); CTRL is a compile-time DPP control code.
template<int CTRL>
__device__ __forceinline__ float dpp_add(float x) {
    int p = __builtin_amdgcn_update_dpp(0, __builtin_bit_cast(int, x),
                                        CTRL, 0xF, 0xF, true);
    return x + __builtin_bit_cast(float, p);
}

// Sum across each aligned 16-lane group; result broadcast to all 16 lanes.
//   0x140 row_mirror (^15), 0x141 row_half_mirror (^7),
//   0x4E quad_perm(2,3,0,1) (^2), 0xB1 quad_perm(1,0,3,2) (^1).
// XOR masks {15,7,2,1} span 4 bits -> every lane gets the full 16-lane sum.
__device__ __forceinline__ float row16_sum(float x) {
    x = dpp_add<0x140>(x);
    x = dpp_add<0x141>(x);
    x = dpp_add<0x4E>(x);
    x = dpp_add<0xB1>(x);
    return x;
}

__device__ __forceinline__ void ccu_body(
    const f32x4 cv, const f32x4 ce,
    const f32x4 wvv, const f32x4 wev, const f32x4 wve, const f32x4 wee,
    const f32x4 bv, const f32x4 be,
    f32x4* __restrict__ out_v, f32x4* __restrict__ out_e, const int g)
{
    // per-lane partial dots + 16-lane row reduction (pure VALU DPP)
    const float s_vv = row16_sum(dot4(ce, wvv));
    const float s_ev = row16_sum(dot4(cv, wev));
    const float s_ve = row16_sum(dot4(ce, wve));
    const float s_ee = row16_sum(dot4(cv, wee));

    // v_out = v*(e.w_vv) + e*(v.w_ev) + bias_v
    // e_out = v*(e.w_ve) + e*(v.w_ee) + bias_e
    f32x4 ov, oe;
#pragma unroll
    for (int j = 0; j < 4; ++j) {
        ov[j] = fmaf(cv[j], s_vv, fmaf(ce[j], s_ev, bv[j]));
        oe[j] = fmaf(cv[j], s_ve, fmaf(ce[j], s_ee, be[j]));
    }

    __builtin_nontemporal_store(ov, &out_v[g]);
    __builtin_nontemporal_store(oe, &out_e[g]);
}

__global__ __launch_bounds__(BLOCK) void ccu_kernel(
    const f32x4* __restrict__ v,       // B*D fp32 as B*16 f32x4
    const f32x4* __restrict__ e,
    const f32x4* __restrict__ w_vv,    // D fp32 as 16 f32x4
    const f32x4* __restrict__ w_ev,
    const f32x4* __restrict__ w_ve,
    const f32x4* __restrict__ w_ee,
    const f32x4* __restrict__ bias_v,
    const f32x4* __restrict__ bias_e,
    f32x4* __restrict__ out_v,
    f32x4* __restrict__ out_e)
{
    const int tid = blockIdx.x * BLOCK + threadIdx.x;
    const int sub = tid & (LANES_PER_ROW - 1);   // chunk index within the row

    // weights + biases: 256B each, cached; loaded once, live for all 8 chunks
    const f32x4 wvv = w_vv[sub];
    const f32x4 wev = w_ev[sub];
    const f32x4 wve = w_ve[sub];
    const f32x4 wee = w_ee[sub];
    const f32x4 bv  = bias_v[sub];
    const f32x4 be  = bias_e[sub];

    // prime the pipeline: chunk 0 in flight
    f32x4 cv = __builtin_nontemporal_load(&v[tid]);
    f32x4 ce = __builtin_nontemporal_load(&e[tid]);

#pragma unroll
    for (int i = 0; i < PER_THREAD - 1; ++i) {
        const int g = tid + i * STRIDE;

        // depth-1 prefetch: issue next chunk's loads before this chunk's
        // compute+store, keeping stream loads continuously in flight
        const f32x4 nv = __builtin_nontemporal_load(&v[g + STRIDE]);
        const f32x4 ne = __builtin_nontemporal_load(&e[g + STRIDE]);

        ccu_body(cv, ce, wvv, wev, wve, wee, bv, be, out_v, out_e, g);

        cv = nv;
        ce = ne;
    }

    // peeled epilogue: last chunk, no prefetch
    ccu_body(cv, ce, wvv, wev, wve, wee, bv, be, out_v, out_e,
             tid + (PER_THREAD - 1) * STRIDE);
}

extern "C" void kernel_launch(void* const* d_in, const int* in_sizes, int n_in,
                              void* d_out, int out_size, void* d_ws, size_t ws_size,
                              hipStream_t stream) {
    const f32x4* v      = (const f32x4*)d_in[0];
    const f32x4* e      = (const f32x4*)d_in[1];
    const f32x4* w_vv   = (const f32x4*)d_in[2];
    const f32x4* w_ev   = (const f32x4*)d_in[3];
    const f32x4* w_ve   = (const f32x4*)d_in[4];
    const f32x4* w_ee   = (const f32x4*)d_in[5];
    const f32x4* bias_v = (const f32x4*)d_in[6];
    const f32x4* bias_e = (const f32x4*)d_in[7];

    f32x4* out_v = (f32x4*)d_out;                    // fp32 v_out
    f32x4* out_e = out_v + (size_t)CHUNKS;           // fp32 e_out

    ccu_kernel<<<NBLOCKS, BLOCK, 0, stream>>>(
        v, e, w_vv, w_ev, w_ve, w_ee, bias_v, bias_e, out_v, out_e);
}